// Round 3
// baseline (88.674 us; speedup 1.0000x reference)
//
#include <hip/hip_runtime.h>

#define TRAIN_ROIS 256
#define POS_QUOTA 25          // int(0.1 * 256)
#define POS_THR 0.5f
#define NEG_THR 0.02f
#define EPS 1e-8f
#define G_MAX 32
#define B_MAX 16

// IoU with arithmetic mirroring the reference exactly (left-assoc products,
// (v1+v2)-inter+eps denominator). Pure mul/sub/div/max: no FMA-contraction
// ambiguity, so recomputation is bit-identical across kernels.
__device__ __forceinline__ float iou3d(const float* __restrict__ g,
                                       const float* __restrict__ b) {
    float lo0 = fmaxf(g[0], b[0]);
    float lo1 = fmaxf(g[1], b[1]);
    float lo2 = fmaxf(g[2], b[2]);
    float hi0 = fminf(g[3], b[3]);
    float hi1 = fminf(g[4], b[4]);
    float hi2 = fminf(g[5], b[5]);
    float d0 = fmaxf(hi0 - lo0, 0.0f);
    float d1 = fmaxf(hi1 - lo1, 0.0f);
    float d2 = fmaxf(hi2 - lo2, 0.0f);
    float inter = (d0 * d1) * d2;
    float v1 = ((g[3] - g[0]) * (g[4] - g[1])) * (g[5] - g[2]);
    float v2 = ((b[3] - b[0]) * (b[4] - b[1])) * (b[5] - b[2]);
    return inter / (((v1 + v2) - inter) + EPS);
}

// Phase A: one thread per proposal. Compute max IoU over the G gts of its own
// image, emit tie bitmask classified pos/neg, and accumulate per-(image,type,g)
// counts via LDS. Full masks (all-G ties, the common iou==0 neg case) are
// counted separately with a single atomic.
__global__ void phaseA(const float* __restrict__ props, const int* __restrict__ bidx,
                       const float* __restrict__ gtb,
                       unsigned int* __restrict__ posBits, unsigned int* __restrict__ negBits,
                       int* __restrict__ gcntPart, int* __restrict__ gcntFull,
                       int P, int B, int G) {
    __shared__ int sc[B_MAX * 2 * G_MAX];
    __shared__ int scFull[B_MAX * 2];
    int tid = threadIdx.x;
    int p = blockIdx.x * blockDim.x + tid;
    int nSlots = B * 2 * G;
    for (int t = tid; t < nSlots; t += blockDim.x) sc[t] = 0;
    for (int t = tid; t < B * 2; t += blockDim.x) scFull[t] = 0;
    __syncthreads();

    if (p < P) {
        int i = bidx[p];
        float b[6];
#pragma unroll
        for (int k = 0; k < 6; ++k) b[k] = props[p * 6 + k];
        const float* gbase = gtb + (size_t)i * G * 6;
        float iou[G_MAX];
        float m = -1e30f;
#pragma unroll
        for (int g = 0; g < G_MAX; ++g) {
            if (g < G) {
                iou[g] = iou3d(gbase + g * 6, b);
                m = fmaxf(m, iou[g]);
            } else {
                iou[g] = -2.0f;
            }
        }
        unsigned int pb = 0, nb = 0;
        if (m >= POS_THR) {
#pragma unroll
            for (int g = 0; g < G_MAX; ++g)
                if (iou[g] == m) pb |= 1u << g;
        } else if (m < NEG_THR) {  // m >= 0 always for in-image proposals
#pragma unroll
            for (int g = 0; g < G_MAX; ++g)
                if (iou[g] == m) nb |= 1u << g;
        }
        posBits[p] = pb;
        negBits[p] = nb;
        unsigned int fullMask = (G >= 32) ? 0xFFFFFFFFu : ((1u << G) - 1u);
        if (pb) {
            if (pb == fullMask) atomicAdd(&scFull[i * 2 + 0], 1);
            else {
                unsigned int t = pb;
                while (t) { int g = __ffs(t) - 1; t &= t - 1; atomicAdd(&sc[(i * 2 + 0) * G + g], 1); }
            }
        }
        if (nb) {
            if (nb == fullMask) atomicAdd(&scFull[i * 2 + 1], 1);
            else {
                unsigned int t = nb;
                while (t) { int g = __ffs(t) - 1; t &= t - 1; atomicAdd(&sc[(i * 2 + 1) * G + g], 1); }
            }
        }
    }
    __syncthreads();
    for (int t = tid; t < nSlots; t += blockDim.x)
        if (sc[t]) atomicAdd(&gcntPart[t], sc[t]);
    for (int t = tid; t < B * 2; t += blockDim.x)
        if (scFull[t]) atomicAdd(&gcntFull[t], scFull[t]);
}

// Phase B: ONE block per (image,type). Maintains per-g {off,need,fill} in LDS
// plus an `active` bitmask of not-yet-filled g's. Single ascending scan over
// proposals; per chunk, ballots only for active g's; ordered placement with
// cross-wave prefix; early-exit when active==0. Pos cap = POS_QUOTA (phaseC
// never reads beyond it), neg cap = TRAIN_ROIS.
__launch_bounds__(1024)
__global__ void fillKernel(const unsigned int* __restrict__ posBits,
                           const unsigned int* __restrict__ negBits,
                           const int* __restrict__ bidx,
                           const int* __restrict__ gcntPart, const int* __restrict__ gcntFull,
                           int* __restrict__ orders, int P, int G) {
    int bid = blockIdx.x;           // i*2 + type
    int type = bid & 1;
    int i = bid >> 1;
    const unsigned int* bits = type ? negBits : posBits;
    int* order = orders + bid * TRAIN_ROIS;
    int cap = type ? TRAIN_ROIS : POS_QUOTA;

    __shared__ int s_off[G_MAX], s_need[G_MAX], s_fill[G_MAX], s_tot[G_MAX];
    __shared__ int s_wcnt[16][G_MAX];
    __shared__ unsigned int s_active;

    int tid = threadIdx.x, lane = tid & 63, wid = tid >> 6;
    if (tid == 0) {
        int full = gcntFull[bid];
        int run = 0;
        unsigned int act = 0;
        for (int g = 0; g < G; ++g) {
            int cnt = gcntPart[bid * G + g] + full;
            s_off[g] = run;
            int need = cap - run;
            if (need < 0) need = 0;
            if (need > cnt) need = cnt;
            s_need[g] = need;
            s_fill[g] = 0;
            if (need > 0) act |= 1u << g;
            run += cnt;
        }
        s_active = act;
    }
    __syncthreads();

    unsigned long long laneLt = (1ull << lane) - 1ull;
    for (int p0 = 0; p0 < P; p0 += 1024) {
        unsigned int active = s_active;
        if (!active) break;
        int p = p0 + tid;
        unsigned int mask = (p < P && bidx[p] == i) ? bits[p] : 0u;
        mask &= active;
        // per-wave counts for active g's
        unsigned int am = active;
        while (am) {
            int g = __ffs(am) - 1; am &= am - 1;
            unsigned long long bal = __ballot((mask >> g) & 1u);
            if (lane == 0) s_wcnt[wid][g] = __popcll(bal);
        }
        __syncthreads();
        // exclusive prefix across the 16 waves, per active g (thread g)
        if (tid < G_MAX && ((active >> tid) & 1u)) {
            int run = 0;
#pragma unroll
            for (int w = 0; w < 16; ++w) {
                int c = s_wcnt[w][tid];
                s_wcnt[w][tid] = run;
                run += c;
            }
            s_tot[tid] = run;
        }
        __syncthreads();
        // placement
        am = active;
        while (am) {
            int g = __ffs(am) - 1; am &= am - 1;
            bool bit = (mask >> g) & 1u;
            unsigned long long bal = __ballot(bit);
            if (!bal) continue;
            if (bit) {
                int laneRank = __popcll(bal & laneLt);
                int rank = s_fill[g] + s_wcnt[wid][g] + laneRank;
                if (rank < s_need[g]) order[s_off[g] + rank] = g * P + p;
            }
        }
        __syncthreads();
        // update fill counts + retire finished g's
        if (tid < G_MAX && ((active >> tid) & 1u)) {
            int f = s_fill[tid] + s_tot[tid];
            s_fill[tid] = f;
            if (f >= s_need[tid]) atomicAnd(&s_active, ~(1u << tid));
        }
        __syncthreads();
    }
}

// Phase C: emit all outputs. out layout: rois[B*256*6] | deltas[B*256*6] |
// labels[B*256] | tag[B*256] | ridx[B*256], all as float32. Totals computed
// in-block from the (capped-sufficient) counts.
__global__ void phaseC(const float* __restrict__ props, const float* __restrict__ gtb,
                       const int* __restrict__ glab,
                       const int* __restrict__ orders,
                       const int* __restrict__ gcntPart, const int* __restrict__ gcntFull,
                       float* __restrict__ out, int P, int G, int B) {
    __shared__ int s_pos_num, s_valid_num;
    int i = blockIdx.x;
    int s = threadIdx.x;
    if (s == 0) {
        int pos_total = 0, neg_total = 0;
        for (int g = 0; g < G; ++g) {
            pos_total += gcntPart[(2 * i + 0) * G + g];
            neg_total += gcntPart[(2 * i + 1) * G + g];
        }
        pos_total += G * gcntFull[2 * i + 0];
        neg_total += G * gcntFull[2 * i + 1];
        if (pos_total > TRAIN_ROIS) pos_total = TRAIN_ROIS;
        if (neg_total > TRAIN_ROIS) neg_total = TRAIN_ROIS;
        int pos_num = pos_total < POS_QUOTA ? pos_total : POS_QUOTA;
        int rem = TRAIN_ROIS - pos_num;
        int neg_num = neg_total < rem ? neg_total : rem;
        s_pos_num = pos_num;
        s_valid_num = pos_num + neg_num;
    }
    __syncthreads();
    int pos_num = s_pos_num;
    bool is_pos = s < pos_num;
    bool valid = s < s_valid_num;
    int t = s - pos_num;
    t = t < 0 ? 0 : (t > TRAIN_ROIS - 1 ? TRAIN_ROIS - 1 : t);
    int idx = is_pos ? orders[(2 * i + 0) * TRAIN_ROIS + s]
                     : orders[(2 * i + 1) * TRAIN_ROIS + t];
    int g = idx / P;
    int p = idx - g * P;
    float b[6], gt[6];
#pragma unroll
    for (int k = 0; k < 6; ++k) {
        b[k] = props[p * 6 + k];
        gt[k] = gtb[((size_t)i * G + g) * 6 + k];
    }
    float vf = valid ? 1.0f : 0.0f;
    int row = i * TRAIN_ROIS + s;
    float* o_rois = out;
    float* o_del = out + (size_t)B * TRAIN_ROIS * 6;
    float* o_lab = o_del + (size_t)B * TRAIN_ROIS * 6;
    float* o_tag = o_lab + (size_t)B * TRAIN_ROIS;
    float* o_ridx = o_tag + (size_t)B * TRAIN_ROIS;
#pragma unroll
    for (int k = 0; k < 6; ++k) o_rois[row * 6 + k] = b[k] * vf;
    float sz0 = b[3] - b[0], sz1 = b[4] - b[1], sz2 = b[5] - b[2];
    float c0 = (b[0] + b[3]) * 0.5f, c1 = (b[1] + b[4]) * 0.5f, c2 = (b[2] + b[5]) * 0.5f;
    float gs0 = gt[3] - gt[0], gs1 = gt[4] - gt[1], gs2 = gt[5] - gt[2];
    float gc0 = (gt[0] + gt[3]) * 0.5f, gc1 = (gt[1] + gt[4]) * 0.5f, gc2 = (gt[2] + gt[5]) * 0.5f;
    float d[6];
    d[0] = (gc0 - c0) / sz0;
    d[1] = (gc1 - c1) / sz1;
    d[2] = (gc2 - c2) / sz2;
    d[3] = logf(gs0 / sz0);
    d[4] = logf(gs1 / sz1);
    d[5] = logf(gs2 / sz2);
#pragma unroll
    for (int k = 0; k < 6; ++k) o_del[row * 6 + k] = d[k] * vf;
    int lab = is_pos ? glab[i * G + g] : 0;
    o_lab[row] = (float)(valid ? lab : 0);
    o_tag[row] = is_pos ? 1.0f : (valid ? -1.0f : 0.0f);
    o_ridx[row] = valid ? (float)i : -1.0f;
}

extern "C" void kernel_launch(void* const* d_in, const int* in_sizes, int n_in,
                              void* d_out, int out_size, void* d_ws, size_t ws_size,
                              hipStream_t stream) {
    const float* props = (const float*)d_in[0];
    const int* bidx = (const int*)d_in[1];
    const float* gtb = (const float*)d_in[2];
    const int* glab = (const int*)d_in[3];
    int P = in_sizes[1];                       // 65536
    int B = out_size / (TRAIN_ROIS * 15);      // 6+6+1+1+1 per slot -> 8
    int G = in_sizes[3] / B;                   // 32

    unsigned int* posBits = (unsigned int*)d_ws;      // [P]
    unsigned int* negBits = posBits + (size_t)P;      // [P]
    int* orders = (int*)(negBits + (size_t)P);        // [B][2][256]
    int* gcntPart = orders + B * 2 * TRAIN_ROIS;      // [B][2][G]
    int* gcntFull = gcntPart + B * 2 * G;             // [B][2]

    // zero orders + counters in one memset node (orders must be 0 so that
    // invalid-slot gathers in phaseC stay in-bounds; counters feed atomics)
    size_t zeroBytes = (size_t)(B * 2 * TRAIN_ROIS + B * 2 * G + B * 2) * sizeof(int);
    hipMemsetAsync(orders, 0, zeroBytes, stream);

    phaseA<<<(P + 255) / 256, 256, 0, stream>>>(props, bidx, gtb, posBits, negBits,
                                                gcntPart, gcntFull, P, B, G);
    fillKernel<<<B * 2, 1024, 0, stream>>>(posBits, negBits, bidx,
                                           gcntPart, gcntFull, orders, P, G);
    phaseC<<<B, TRAIN_ROIS, 0, stream>>>(props, gtb, glab, orders,
                                         gcntPart, gcntFull, (float*)d_out, P, G, B);
}

// Round 4
// 49.527 us; speedup vs baseline: 1.7904x; 1.7904x over previous
//
#include <hip/hip_runtime.h>

#define TRAIN_ROIS 256
#define POS_QUOTA 25          // int(0.1 * 256)
#define POS_THR 0.5f
#define NEG_THR 0.02f
#define EPS 1e-8f
#define G_MAX 32
#define B_MAX 16
#define SEG 1024              // proposals per segment (= placeKernel block size)

// IoU with arithmetic mirroring the reference exactly (left-assoc products,
// (v1+v2)-inter+eps denominator). Pure mul/sub/div/max: no FMA-contraction
// ambiguity, so recomputation is bit-identical across kernels.
__device__ __forceinline__ float iou3d(const float* __restrict__ g,
                                       const float* __restrict__ b) {
    float lo0 = fmaxf(g[0], b[0]);
    float lo1 = fmaxf(g[1], b[1]);
    float lo2 = fmaxf(g[2], b[2]);
    float hi0 = fminf(g[3], b[3]);
    float hi1 = fminf(g[4], b[4]);
    float hi2 = fminf(g[5], b[5]);
    float d0 = fmaxf(hi0 - lo0, 0.0f);
    float d1 = fmaxf(hi1 - lo1, 0.0f);
    float d2 = fmaxf(hi2 - lo2, 0.0f);
    float inter = (d0 * d1) * d2;
    float v1 = ((g[3] - g[0]) * (g[4] - g[1])) * (g[5] - g[2]);
    float v2 = ((b[3] - b[0]) * (b[4] - b[1])) * (b[5] - b[2]);
    return inter / (((v1 + v2) - inter) + EPS);
}

// Phase A: one thread per proposal (block = one 1024-p segment). Computes the
// pos/neg tie bitmask and PER-SEGMENT counts (plain stores, no global atomics).
// gt boxes staged in LDS (wave-broadcast reads). Full-mask (all-G tie, the
// common iou==0 neg case) counted separately: one atomic instead of 32.
__launch_bounds__(1024)
__global__ void phaseA(const float* __restrict__ props, const int* __restrict__ bidx,
                       const float* __restrict__ gtb,
                       unsigned int* __restrict__ posBits, unsigned int* __restrict__ negBits,
                       int* __restrict__ gcntSeg, int* __restrict__ gcntFullSeg,
                       int P, int B, int G, int ITS) {
    __shared__ int sc[B_MAX * 2 * G_MAX];
    __shared__ int scFull[B_MAX * 2];
    __shared__ float s_gtb[B_MAX * G_MAX * 6];
    int tid = threadIdx.x;
    int seg = blockIdx.x;
    int p = seg * SEG + tid;
    int nSlots = ITS * G_MAX;
    for (int t = tid; t < nSlots; t += blockDim.x) sc[t] = 0;
    if (tid < ITS) scFull[tid] = 0;
    for (int t = tid; t < B * G * 6; t += blockDim.x) s_gtb[t] = gtb[t];
    __syncthreads();

    if (p < P) {
        int i = bidx[p];
        const float2* pp = reinterpret_cast<const float2*>(props + (size_t)p * 6);
        float2 a0 = pp[0], a1 = pp[1], a2 = pp[2];
        float b[6] = {a0.x, a0.y, a1.x, a1.y, a2.x, a2.y};
        const float* gbase = s_gtb + i * G * 6;
        float iou[G_MAX];
        float m = -1e30f;
#pragma unroll
        for (int g = 0; g < G_MAX; ++g) {
            if (g < G) {
                iou[g] = iou3d(gbase + g * 6, b);
                m = fmaxf(m, iou[g]);
            } else {
                iou[g] = -2.0f;
            }
        }
        unsigned int pb = 0, nb = 0;
        if (m >= POS_THR) {
#pragma unroll
            for (int g = 0; g < G_MAX; ++g)
                if (iou[g] == m) pb |= 1u << g;
        } else if (m < NEG_THR) {  // m >= 0 always for in-image proposals
#pragma unroll
            for (int g = 0; g < G_MAX; ++g)
                if (iou[g] == m) nb |= 1u << g;
        }
        posBits[p] = pb;
        negBits[p] = nb;
        unsigned int fullMask = (G >= 32) ? 0xFFFFFFFFu : ((1u << G) - 1u);
        if (pb) {
            if (pb == fullMask) atomicAdd(&scFull[i * 2 + 0], 1);
            else {
                unsigned int t = pb;
                while (t) { int g = __ffs(t) - 1; t &= t - 1; atomicAdd(&sc[(i * 2 + 0) * G_MAX + g], 1); }
            }
        }
        if (nb) {
            if (nb == fullMask) atomicAdd(&scFull[i * 2 + 1], 1);
            else {
                unsigned int t = nb;
                while (t) { int g = __ffs(t) - 1; t &= t - 1; atomicAdd(&sc[(i * 2 + 1) * G_MAX + g], 1); }
            }
        }
    }
    __syncthreads();
    for (int t = tid; t < nSlots; t += blockDim.x)
        gcntSeg[seg * nSlots + t] = sc[t];
    if (tid < ITS) gcntFullSeg[seg * ITS + tid] = scFull[tid];
}

// Scan: one block, thread = (it,g). Exclusive prefix of per-segment counts
// (partial + full) over segments -> startRank; then per-it prefix over g ->
// off/need (capped: pos cap = POS_QUOTA, neg cap = TRAIN_ROIS) and totals.
__global__ void scanKernel(const int* __restrict__ gcntSeg, const int* __restrict__ gcntFullSeg,
                           int* __restrict__ startRank, int* __restrict__ offA,
                           int* __restrict__ needA, int* __restrict__ totals,
                           int NSEG, int G, int ITS) {
    int tid = threadIdx.x;            // it*G_MAX + g
    int it = tid >> 5, g = tid & 31;
    int nSlots = ITS * G_MAX;
    __shared__ int s_tot[B_MAX * 2 * G_MAX];
    int run = 0;
    for (int s = 0; s < NSEG; ++s) {
        startRank[s * nSlots + tid] = run;
        run += gcntSeg[s * nSlots + tid] + gcntFullSeg[s * ITS + it];
    }
    s_tot[tid] = (g < G) ? run : 0;
    __syncthreads();
    int base = 0;
    for (int gg = 0; gg < g; ++gg) base += s_tot[(it << 5) | gg];
    int cap = (it & 1) ? TRAIN_ROIS : POS_QUOTA;
    int total = s_tot[tid];
    int nd = cap - base;
    if (nd < 0) nd = 0;
    if (nd > total) nd = total;
    offA[tid] = base;
    needA[tid] = nd;
    if (g == G - 1) {
        int tot = base + total;
        if (tot > TRAIN_ROIS) tot = TRAIN_ROIS;
        totals[it] = tot;
    }
}

// Place: one block per (segment, it). Single ballot pass over its 1024
// proposals; global rank = startRank[seg][it][g] + intra-segment ordered rank.
// Blocks whose g's are all already satisfied exit immediately.
__launch_bounds__(1024)
__global__ void placeKernel(const unsigned int* __restrict__ posBits,
                            const unsigned int* __restrict__ negBits,
                            const int* __restrict__ bidx,
                            const int* __restrict__ startRank, const int* __restrict__ offA,
                            const int* __restrict__ needA,
                            int* __restrict__ orders, int P, int G, int ITS) {
    int blk = blockIdx.x;
    int seg = blk / ITS;
    int it = blk - seg * ITS;
    int type = it & 1;
    int i = it >> 1;
    int nSlots = ITS * G_MAX;

    __shared__ int s_srk[G_MAX], s_off[G_MAX], s_need[G_MAX];
    __shared__ unsigned int s_active;
    __shared__ int s_wcnt[16][G_MAX];

    int tid = threadIdx.x, lane = tid & 63, wid = tid >> 6;
    if (tid < G_MAX) {
        int sr = startRank[seg * nSlots + it * G_MAX + tid];
        int nd = needA[it * G_MAX + tid];
        s_srk[tid] = sr;
        s_off[tid] = offA[it * G_MAX + tid];
        s_need[tid] = nd;
        unsigned long long bal = __ballot(sr < nd);
        if (tid == 0) s_active = (unsigned int)bal;
    }
    __syncthreads();
    unsigned int active = s_active;
    if (!active) return;

    int p = seg * SEG + tid;
    unsigned int mask = 0;
    if (p < P && bidx[p] == i)
        mask = (type ? negBits : posBits)[p] & active;

    // per-wave counts for active g's
    unsigned int am = active;
    while (am) {
        int g = __ffs(am) - 1; am &= am - 1;
        unsigned long long bal = __ballot((mask >> g) & 1u);
        if (lane == 0) s_wcnt[wid][g] = __popcll(bal);
    }
    __syncthreads();
    // exclusive prefix across the 16 waves (thread g handles bucket g)
    if (tid < G_MAX && ((active >> tid) & 1u)) {
        int run = 0;
#pragma unroll
        for (int w = 0; w < 16; ++w) {
            int c = s_wcnt[w][tid];
            s_wcnt[w][tid] = run;
            run += c;
        }
    }
    __syncthreads();
    // placement
    unsigned long long laneLt = (1ull << lane) - 1ull;
    am = active;
    while (am) {
        int g = __ffs(am) - 1; am &= am - 1;
        bool bit = (mask >> g) & 1u;
        unsigned long long bal = __ballot(bit);
        if (bit) {
            int r = s_srk[g] + s_wcnt[wid][g] + __popcll(bal & laneLt);
            if (r < s_need[g]) orders[it * TRAIN_ROIS + s_off[g] + r] = g * P + p;
        }
    }
}

// Phase C: emit all outputs. out layout: rois[B*256*6] | deltas[B*256*6] |
// labels[B*256] | tag[B*256] | ridx[B*256], all float32. Invalid slots force
// idx=0 (so `orders` needs no zero-init; outputs are masked by vf anyway).
__global__ void phaseC(const float* __restrict__ props, const float* __restrict__ gtb,
                       const int* __restrict__ glab,
                       const int* __restrict__ orders, const int* __restrict__ totals,
                       float* __restrict__ out, int P, int G, int B) {
    int i = blockIdx.x;
    int s = threadIdx.x;
    int pos_total = totals[2 * i + 0];
    int neg_total = totals[2 * i + 1];
    int pos_num = pos_total < POS_QUOTA ? pos_total : POS_QUOTA;
    int rem = TRAIN_ROIS - pos_num;
    int neg_num = neg_total < rem ? neg_total : rem;
    bool is_pos = s < pos_num;
    bool valid = s < pos_num + neg_num;
    int t = s - pos_num;
    t = t < 0 ? 0 : t;
    int idx = 0;
    if (valid)
        idx = is_pos ? orders[(2 * i + 0) * TRAIN_ROIS + s]
                     : orders[(2 * i + 1) * TRAIN_ROIS + t];
    int g = idx / P;
    int p = idx - g * P;
    float b[6], gt[6];
#pragma unroll
    for (int k = 0; k < 6; ++k) {
        b[k] = props[(size_t)p * 6 + k];
        gt[k] = gtb[((size_t)i * G + g) * 6 + k];
    }
    float vf = valid ? 1.0f : 0.0f;
    int row = i * TRAIN_ROIS + s;
    float* o_rois = out;
    float* o_del = out + (size_t)B * TRAIN_ROIS * 6;
    float* o_lab = o_del + (size_t)B * TRAIN_ROIS * 6;
    float* o_tag = o_lab + (size_t)B * TRAIN_ROIS;
    float* o_ridx = o_tag + (size_t)B * TRAIN_ROIS;
#pragma unroll
    for (int k = 0; k < 6; ++k) o_rois[row * 6 + k] = b[k] * vf;
    float sz0 = b[3] - b[0], sz1 = b[4] - b[1], sz2 = b[5] - b[2];
    float c0 = (b[0] + b[3]) * 0.5f, c1 = (b[1] + b[4]) * 0.5f, c2 = (b[2] + b[5]) * 0.5f;
    float gs0 = gt[3] - gt[0], gs1 = gt[4] - gt[1], gs2 = gt[5] - gt[2];
    float gc0 = (gt[0] + gt[3]) * 0.5f, gc1 = (gt[1] + gt[4]) * 0.5f, gc2 = (gt[2] + gt[5]) * 0.5f;
    float d[6];
    d[0] = (gc0 - c0) / sz0;
    d[1] = (gc1 - c1) / sz1;
    d[2] = (gc2 - c2) / sz2;
    d[3] = logf(gs0 / sz0);
    d[4] = logf(gs1 / sz1);
    d[5] = logf(gs2 / sz2);
#pragma unroll
    for (int k = 0; k < 6; ++k) o_del[row * 6 + k] = d[k] * vf;
    int lab = is_pos ? glab[i * G + g] : 0;
    o_lab[row] = (float)(valid ? lab : 0);
    o_tag[row] = is_pos ? 1.0f : (valid ? -1.0f : 0.0f);
    o_ridx[row] = valid ? (float)i : -1.0f;
}

extern "C" void kernel_launch(void* const* d_in, const int* in_sizes, int n_in,
                              void* d_out, int out_size, void* d_ws, size_t ws_size,
                              hipStream_t stream) {
    const float* props = (const float*)d_in[0];
    const int* bidx = (const int*)d_in[1];
    const float* gtb = (const float*)d_in[2];
    const int* glab = (const int*)d_in[3];
    int P = in_sizes[1];                       // 65536
    int B = out_size / (TRAIN_ROIS * 15);      // 6+6+1+1+1 per slot -> 8
    int G = in_sizes[3] / B;                   // 32
    int ITS = B * 2;                           // 16
    int NSEG = (P + SEG - 1) / SEG;            // 64
    int nSlots = ITS * G_MAX;                  // 512

    unsigned int* posBits = (unsigned int*)d_ws;          // [P]
    unsigned int* negBits = posBits + (size_t)P;          // [P]
    int* orders = (int*)(negBits + (size_t)P);            // [ITS][256]
    int* gcntSeg = orders + ITS * TRAIN_ROIS;             // [NSEG][ITS][32]
    int* gcntFullSeg = gcntSeg + (size_t)NSEG * nSlots;   // [NSEG][ITS]
    int* startRank = gcntFullSeg + (size_t)NSEG * ITS;    // [NSEG][ITS][32]
    int* offA = startRank + (size_t)NSEG * nSlots;        // [ITS][32]
    int* needA = offA + nSlots;                           // [ITS][32]
    int* totals = needA + nSlots;                         // [ITS]

    phaseA<<<NSEG, SEG, 0, stream>>>(props, bidx, gtb, posBits, negBits,
                                     gcntSeg, gcntFullSeg, P, B, G, ITS);
    scanKernel<<<1, nSlots, 0, stream>>>(gcntSeg, gcntFullSeg, startRank,
                                         offA, needA, totals, NSEG, G, ITS);
    placeKernel<<<NSEG * ITS, SEG, 0, stream>>>(posBits, negBits, bidx,
                                                startRank, offA, needA,
                                                orders, P, G, ITS);
    phaseC<<<B, TRAIN_ROIS, 0, stream>>>(props, gtb, glab, orders, totals,
                                         (float*)d_out, P, G, B);
}

// Round 5
// 39.542 us; speedup vs baseline: 2.2425x; 1.2525x over previous
//
#include <hip/hip_runtime.h>

#define TRAIN_ROIS 256
#define POS_QUOTA 25          // int(0.1 * 256)
#define POS_THR 0.5f
#define NEG_THR 0.02f
#define EPS 1e-8f
#define G_MAX 32
#define B_MAX 16
#define SEG 1024              // proposals per segment (= block size of A/place)

// IoU with arithmetic mirroring the reference exactly (left-assoc products,
// (v1+v2)-inter+eps denominator). Pure mul/sub/div/max: no FMA-contraction
// ambiguity, so recomputation is bit-identical across kernels.
__device__ __forceinline__ float iou3d(const float* __restrict__ g,
                                       const float* __restrict__ b) {
    float lo0 = fmaxf(g[0], b[0]);
    float lo1 = fmaxf(g[1], b[1]);
    float lo2 = fmaxf(g[2], b[2]);
    float hi0 = fminf(g[3], b[3]);
    float hi1 = fminf(g[4], b[4]);
    float hi2 = fminf(g[5], b[5]);
    float d0 = fmaxf(hi0 - lo0, 0.0f);
    float d1 = fmaxf(hi1 - lo1, 0.0f);
    float d2 = fmaxf(hi2 - lo2, 0.0f);
    float inter = (d0 * d1) * d2;
    float v1 = ((g[3] - g[0]) * (g[4] - g[1])) * (g[5] - g[2]);
    float v2 = ((b[3] - b[0]) * (b[4] - b[1])) * (b[5] - b[2]);
    return inter / (((v1 + v2) - inter) + EPS);
}

// Phase A: one thread per proposal (block = one 1024-p segment). Computes the
// pos/neg tie bitmask and PER-SEGMENT counts, stored TRANSPOSED
// (gcntSegT[slot][seg], slot = it*32+g) so placeKernel reads contiguous rows.
// Full-mask (all-G tie, the common iou==0 neg case) counted separately.
__launch_bounds__(1024)
__global__ void phaseA(const float* __restrict__ props, const int* __restrict__ bidx,
                       const float* __restrict__ gtb,
                       unsigned int* __restrict__ posBits, unsigned int* __restrict__ negBits,
                       int* __restrict__ gcntSegT, int* __restrict__ gcntFullSegT,
                       int P, int B, int G, int ITS, int NSEG) {
    __shared__ int sc[B_MAX * 2 * G_MAX];
    __shared__ int scFull[B_MAX * 2];
    __shared__ float s_gtb[B_MAX * G_MAX * 6];
    int tid = threadIdx.x;
    int seg = blockIdx.x;
    int p = seg * SEG + tid;
    int nSlots = ITS * G_MAX;
    for (int t = tid; t < nSlots; t += blockDim.x) sc[t] = 0;
    if (tid < ITS) scFull[tid] = 0;
    for (int t = tid; t < B * G * 6; t += blockDim.x) s_gtb[t] = gtb[t];
    __syncthreads();

    if (p < P) {
        int i = bidx[p];
        const float2* pp = reinterpret_cast<const float2*>(props + (size_t)p * 6);
        float2 a0 = pp[0], a1 = pp[1], a2 = pp[2];
        float b[6] = {a0.x, a0.y, a1.x, a1.y, a2.x, a2.y};
        const float* gbase = s_gtb + i * G * 6;
        float iou[G_MAX];
        float m = -1e30f;
#pragma unroll
        for (int g = 0; g < G_MAX; ++g) {
            if (g < G) {
                iou[g] = iou3d(gbase + g * 6, b);
                m = fmaxf(m, iou[g]);
            } else {
                iou[g] = -2.0f;
            }
        }
        unsigned int pb = 0, nb = 0;
        if (m >= POS_THR) {
#pragma unroll
            for (int g = 0; g < G_MAX; ++g)
                if (iou[g] == m) pb |= 1u << g;
        } else if (m < NEG_THR) {  // m >= 0 always for in-image proposals
#pragma unroll
            for (int g = 0; g < G_MAX; ++g)
                if (iou[g] == m) nb |= 1u << g;
        }
        posBits[p] = pb;
        negBits[p] = nb;
        unsigned int fullMask = (G >= 32) ? 0xFFFFFFFFu : ((1u << G) - 1u);
        if (pb) {
            if (pb == fullMask) atomicAdd(&scFull[i * 2 + 0], 1);
            else {
                unsigned int t = pb;
                while (t) { int g = __ffs(t) - 1; t &= t - 1; atomicAdd(&sc[(i * 2 + 0) * G_MAX + g], 1); }
            }
        }
        if (nb) {
            if (nb == fullMask) atomicAdd(&scFull[i * 2 + 1], 1);
            else {
                unsigned int t = nb;
                while (t) { int g = __ffs(t) - 1; t &= t - 1; atomicAdd(&sc[(i * 2 + 1) * G_MAX + g], 1); }
            }
        }
    }
    __syncthreads();
    for (int t = tid; t < nSlots; t += blockDim.x)
        gcntSegT[(size_t)t * NSEG + seg] = sc[t];
    if (tid < ITS) gcntFullSegT[(size_t)tid * NSEG + seg] = scFull[tid];
}

// Place: one block per (segment, it). Each block recomputes its own prefix:
// threads 0..31 sum their g-row (contiguous, int4-vectorized, one parallel
// memory round-trip); thread 32 sums the full-mask row; then a 32-step LDS
// prefix over g yields off/need/startRank. Block (seg=0,it) writes totals.
// Then a single ballot pass places this segment's matches at
// rank = startRank + intra-segment ordered rank.
__launch_bounds__(1024)
__global__ void placeKernel(const unsigned int* __restrict__ posBits,
                            const unsigned int* __restrict__ negBits,
                            const int* __restrict__ bidx,
                            const int* __restrict__ gcntSegT, const int* __restrict__ gcntFullSegT,
                            int* __restrict__ orders, int* __restrict__ totals,
                            int P, int G, int ITS, int NSEG) {
    int blk = blockIdx.x;
    int seg = blk / ITS;
    int it = blk - seg * ITS;
    int type = it & 1;
    int i = it >> 1;

    __shared__ int s_rowTot[G_MAX], s_rowPre[G_MAX];
    __shared__ int s_fullTot, s_fullPre;
    __shared__ int s_srk[G_MAX], s_off[G_MAX], s_need[G_MAX];
    __shared__ unsigned int s_active;
    __shared__ int s_wcnt[16][G_MAX];

    int tid = threadIdx.x, lane = tid & 63, wid = tid >> 6;

    if (tid < G_MAX) {
        const int* row = gcntSegT + (size_t)(it * G_MAX + tid) * NSEG;
        int tot = 0, pre = 0;
        if ((NSEG & 3) == 0) {
#pragma unroll 8
            for (int s = 0; s < NSEG; s += 4) {
                int4 v = *reinterpret_cast<const int4*>(row + s);
                int q = v.x + v.y + v.z + v.w;
                tot += q;
                if (s + 4 <= seg) pre += q;
                else if (s < seg) {
                    if (s + 0 < seg) pre += v.x;
                    if (s + 1 < seg) pre += v.y;
                    if (s + 2 < seg) pre += v.z;
                }
            }
        } else {
#pragma unroll 8
            for (int s = 0; s < NSEG; ++s) { int v = row[s]; tot += v; if (s < seg) pre += v; }
        }
        s_rowTot[tid] = tot;
        s_rowPre[tid] = pre;
    } else if (tid == G_MAX) {
        const int* frow = gcntFullSegT + (size_t)it * NSEG;
        int tot = 0, pre = 0;
        if ((NSEG & 3) == 0) {
#pragma unroll 8
            for (int s = 0; s < NSEG; s += 4) {
                int4 v = *reinterpret_cast<const int4*>(frow + s);
                int q = v.x + v.y + v.z + v.w;
                tot += q;
                if (s + 4 <= seg) pre += q;
                else if (s < seg) {
                    if (s + 0 < seg) pre += v.x;
                    if (s + 1 < seg) pre += v.y;
                    if (s + 2 < seg) pre += v.z;
                }
            }
        } else {
#pragma unroll 8
            for (int s = 0; s < NSEG; ++s) { int v = frow[s]; tot += v; if (s < seg) pre += v; }
        }
        s_fullTot = tot;
        s_fullPre = pre;
    }
    __syncthreads();

    if (tid < G_MAX) {
        int fullTot = s_fullTot, fullPre = s_fullPre;
        int base = 0;
        for (int gg = 0; gg < tid; ++gg)
            base += (gg < G) ? (s_rowTot[gg] + fullTot) : 0;
        int totalG = (tid < G) ? (s_rowTot[tid] + fullTot) : 0;
        int cap = type ? TRAIN_ROIS : POS_QUOTA;
        int nd = cap - base;
        if (nd < 0) nd = 0;
        if (nd > totalG) nd = totalG;
        int srk = s_rowPre[tid] + fullPre;
        s_off[tid] = base;
        s_need[tid] = nd;
        s_srk[tid] = srk;
        if (seg == 0 && tid == G - 1) {
            int tot = base + totalG;
            totals[it] = tot > TRAIN_ROIS ? TRAIN_ROIS : tot;
        }
        unsigned long long bal = __ballot(srk < nd);
        if (tid == 0) s_active = (unsigned int)bal;
    }
    __syncthreads();
    unsigned int active = s_active;
    if (!active) return;

    int p = seg * SEG + tid;
    unsigned int mask = 0;
    if (p < P && bidx[p] == i)
        mask = (type ? negBits : posBits)[p] & active;

    // per-wave counts for active g's
    unsigned int am = active;
    while (am) {
        int g = __ffs(am) - 1; am &= am - 1;
        unsigned long long bal = __ballot((mask >> g) & 1u);
        if (lane == 0) s_wcnt[wid][g] = __popcll(bal);
    }
    __syncthreads();
    // exclusive prefix across the 16 waves (thread g handles bucket g)
    if (tid < G_MAX && ((active >> tid) & 1u)) {
        int run = 0;
#pragma unroll
        for (int w = 0; w < 16; ++w) {
            int c = s_wcnt[w][tid];
            s_wcnt[w][tid] = run;
            run += c;
        }
    }
    __syncthreads();
    // placement
    unsigned long long laneLt = (1ull << lane) - 1ull;
    am = active;
    while (am) {
        int g = __ffs(am) - 1; am &= am - 1;
        bool bit = (mask >> g) & 1u;
        unsigned long long bal = __ballot(bit);
        if (bit) {
            int r = s_srk[g] + s_wcnt[wid][g] + __popcll(bal & laneLt);
            if (r < s_need[g]) orders[it * TRAIN_ROIS + s_off[g] + r] = g * P + p;
        }
    }
}

// Phase C: emit all outputs. out layout: rois[B*256*6] | deltas[B*256*6] |
// labels[B*256] | tag[B*256] | ridx[B*256], all float32. Invalid slots force
// idx=0 (so `orders` needs no zero-init; outputs are masked by vf anyway).
__global__ void phaseC(const float* __restrict__ props, const float* __restrict__ gtb,
                       const int* __restrict__ glab,
                       const int* __restrict__ orders, const int* __restrict__ totals,
                       float* __restrict__ out, int P, int G, int B) {
    int i = blockIdx.x;
    int s = threadIdx.x;
    int pos_total = totals[2 * i + 0];
    int neg_total = totals[2 * i + 1];
    int pos_num = pos_total < POS_QUOTA ? pos_total : POS_QUOTA;
    int rem = TRAIN_ROIS - pos_num;
    int neg_num = neg_total < rem ? neg_total : rem;
    bool is_pos = s < pos_num;
    bool valid = s < pos_num + neg_num;
    int t = s - pos_num;
    t = t < 0 ? 0 : t;
    int idx = 0;
    if (valid)
        idx = is_pos ? orders[(2 * i + 0) * TRAIN_ROIS + s]
                     : orders[(2 * i + 1) * TRAIN_ROIS + t];
    int g = idx / P;
    int p = idx - g * P;
    float b[6], gt[6];
#pragma unroll
    for (int k = 0; k < 6; ++k) {
        b[k] = props[(size_t)p * 6 + k];
        gt[k] = gtb[((size_t)i * G + g) * 6 + k];
    }
    float vf = valid ? 1.0f : 0.0f;
    int row = i * TRAIN_ROIS + s;
    float* o_rois = out;
    float* o_del = out + (size_t)B * TRAIN_ROIS * 6;
    float* o_lab = o_del + (size_t)B * TRAIN_ROIS * 6;
    float* o_tag = o_lab + (size_t)B * TRAIN_ROIS;
    float* o_ridx = o_tag + (size_t)B * TRAIN_ROIS;
#pragma unroll
    for (int k = 0; k < 6; ++k) o_rois[row * 6 + k] = b[k] * vf;
    float sz0 = b[3] - b[0], sz1 = b[4] - b[1], sz2 = b[5] - b[2];
    float c0 = (b[0] + b[3]) * 0.5f, c1 = (b[1] + b[4]) * 0.5f, c2 = (b[2] + b[5]) * 0.5f;
    float gs0 = gt[3] - gt[0], gs1 = gt[4] - gt[1], gs2 = gt[5] - gt[2];
    float gc0 = (gt[0] + gt[3]) * 0.5f, gc1 = (gt[1] + gt[4]) * 0.5f, gc2 = (gt[2] + gt[5]) * 0.5f;
    float d[6];
    d[0] = (gc0 - c0) / sz0;
    d[1] = (gc1 - c1) / sz1;
    d[2] = (gc2 - c2) / sz2;
    d[3] = logf(gs0 / sz0);
    d[4] = logf(gs1 / sz1);
    d[5] = logf(gs2 / sz2);
#pragma unroll
    for (int k = 0; k < 6; ++k) o_del[row * 6 + k] = d[k] * vf;
    int lab = is_pos ? glab[i * G + g] : 0;
    o_lab[row] = (float)(valid ? lab : 0);
    o_tag[row] = is_pos ? 1.0f : (valid ? -1.0f : 0.0f);
    o_ridx[row] = valid ? (float)i : -1.0f;
}

extern "C" void kernel_launch(void* const* d_in, const int* in_sizes, int n_in,
                              void* d_out, int out_size, void* d_ws, size_t ws_size,
                              hipStream_t stream) {
    const float* props = (const float*)d_in[0];
    const int* bidx = (const int*)d_in[1];
    const float* gtb = (const float*)d_in[2];
    const int* glab = (const int*)d_in[3];
    int P = in_sizes[1];                       // 65536
    int B = out_size / (TRAIN_ROIS * 15);      // 6+6+1+1+1 per slot -> 8
    int G = in_sizes[3] / B;                   // 32
    int ITS = B * 2;                           // 16
    int NSEG = (P + SEG - 1) / SEG;            // 64
    int nSlots = ITS * G_MAX;                  // 512

    unsigned int* posBits = (unsigned int*)d_ws;            // [P]
    unsigned int* negBits = posBits + (size_t)P;            // [P]
    int* orders = (int*)(negBits + (size_t)P);              // [ITS][256]
    int* gcntSegT = orders + ITS * TRAIN_ROIS;              // [nSlots][NSEG]
    int* gcntFullSegT = gcntSegT + (size_t)nSlots * NSEG;   // [ITS][NSEG]
    int* totals = gcntFullSegT + (size_t)ITS * NSEG;        // [ITS]

    phaseA<<<NSEG, SEG, 0, stream>>>(props, bidx, gtb, posBits, negBits,
                                     gcntSegT, gcntFullSegT, P, B, G, ITS, NSEG);
    placeKernel<<<NSEG * ITS, SEG, 0, stream>>>(posBits, negBits, bidx,
                                                gcntSegT, gcntFullSegT,
                                                orders, totals, P, G, ITS, NSEG);
    phaseC<<<B, TRAIN_ROIS, 0, stream>>>(props, gtb, glab, orders, totals,
                                         (float*)d_out, P, G, B);
}